// Round 2
// baseline (190.754 us; speedup 1.0000x reference)
//
#include <hip/hip_runtime.h>

// LocalEnergyOpt R2: single coalesced float4 stream over the [10000,9] feature
// rows, demuxing columns 5-8 into LDS (coords fp32, connectivity packed u16).
// Floor: 92 MB features @ 6.3 TB/s ~= 15 us. R1 was latency-bound on strided
// scalar gathers (138 MB fetch, 31% BW); this fetches each line exactly once.

#define BS 512

constexpr int MAXLEN  = 10000;
constexpr int N_ATOMS = 2000;
constexpr int NBT = 50, NAT = 100, NTT = 200;
constexpr float EPS = 1e-8f;

// LDS layout (bytes). Indices/types are < 2000 -> exact in ushort.
constexpr int OFF_SC  = 0;                   // 6000 floats: flat coords
constexpr int OFF_SBP = OFF_SC  + 6000 * 4;  // 150 floats: bond params
constexpr int OFF_SAP = OFF_SBP + 150 * 4;   // 300 floats: angle params
constexpr int OFF_STP = OFF_SAP + 300 * 4;   // 600 floats: torsion params
constexpr int OFF_SW  = OFF_STP + 600 * 4;   // 16 floats: wave partials
constexpr int OFF_SB  = OFF_SW  + 16 * 4;    // 6000 u16: bond raw (5997 used)
constexpr int OFF_SA  = OFF_SB  + 6000 * 2;  // 8000 u16: angle raw (7992 used)
constexpr int OFF_ST  = OFF_SA  + 8000 * 2;  // 9988 u16: torsion raw (9985 used)
constexpr int SMEM_BYTES = OFF_ST + 9988 * 2;  // 76240 B -> 2 blocks/CU

__global__ __launch_bounds__(BS) void energy_kernel(
    const float* __restrict__ features,   // [B, 10000, 9]
    const int*   __restrict__ lengths,    // [B, 9]
    const float* __restrict__ opt_pars,   // [350, 3]
    const float* __restrict__ bond_type,  // [50]
    const float* __restrict__ angle_type, // [100]
    const float* __restrict__ tor_type,   // [200]
    float*       __restrict__ out)        // [B]
{
    extern __shared__ char smem[];
    float*          sc  = (float*)(smem + OFF_SC);
    float*          sbp = (float*)(smem + OFF_SBP);
    float*          sap = (float*)(smem + OFF_SAP);
    float*          stp = (float*)(smem + OFF_STP);
    float*          sw  = (float*)(smem + OFF_SW);
    unsigned short* sb  = (unsigned short*)(smem + OFF_SB);
    unsigned short* sa  = (unsigned short*)(smem + OFF_SA);
    unsigned short* st  = (unsigned short*)(smem + OFF_ST);

    const int b   = blockIdx.x;
    const int tid = threadIdx.x;

    // ---- stage resolved param tables (tiny) ----
    for (int i = tid; i < NBT; i += BS) {
        int idx = (int)bond_type[i];
        sbp[3*i+0] = opt_pars[3*idx+0];
        sbp[3*i+1] = opt_pars[3*idx+1];
        sbp[3*i+2] = opt_pars[3*idx+2];
    }
    for (int i = tid; i < NAT; i += BS) {
        int idx = (int)angle_type[i];
        sap[3*i+0] = opt_pars[3*idx+0];
        sap[3*i+1] = opt_pars[3*idx+1];
        sap[3*i+2] = opt_pars[3*idx+2];
    }
    for (int i = tid; i < NTT; i += BS) {
        int idx = (int)tor_type[i];
        stp[3*i+0] = opt_pars[3*idx+0];
        stp[3*i+1] = opt_pars[3*idx+1];
        stp[3*i+2] = opt_pars[3*idx+2];
    }

    // ---- coalesced stream of this system's 90000 floats, demux by col ----
    const float4* __restrict__ fv =
        (const float4*)(features + (size_t)b * MAXLEN * 9);  // 16B-aligned

    auto put = [&](unsigned g, float val) {
        unsigned i   = g / 9u;          // record-flat index within column
        unsigned col = g - 9u * i;
        if (col == 5u)      { if (i < 6000u) sc[i] = val; }
        else if (col == 6u) { if (i < 5997u) sb[i] = (unsigned short)(int)val; }
        else if (col == 7u) { if (i < 7992u) sa[i] = (unsigned short)(int)val; }
        else if (col == 8u) { if (i < 9985u) st[i] = (unsigned short)(int)val; }
    };

    constexpr int NV = MAXLEN * 9 / 4;  // 22500 float4 per system
    #pragma unroll 4
    for (int q = tid; q < NV; q += BS) {
        float4 v = fv[q];
        unsigned g0 = 4u * (unsigned)q;
        put(g0 + 0u, v.x);
        put(g0 + 1u, v.y);
        put(g0 + 2u, v.z);
        put(g0 + 3u, v.w);
    }
    __syncthreads();

    float acc = 0.0f;

    // ---- bonds: E = k * (r - r0)^2 ----
    {
        const int nb = lengths[b * 9 + 6] / 3;
        for (int t = tid; t < nb; t += BS) {
            int i  = sb[3*t+0];
            int j  = sb[3*t+1];
            int ty = sb[3*t+2];
            float dx = sc[3*i+0] - sc[3*j+0];
            float dy = sc[3*i+1] - sc[3*j+1];
            float dz = sc[3*i+2] - sc[3*j+2];
            float r  = sqrtf(dx*dx + dy*dy + dz*dz + EPS);
            float k  = sbp[3*ty+0];
            float d  = r - sbp[3*ty+1];
            acc += k * d * d;
        }
    }

    // ---- angles: E = k * (theta - theta0)^2 ----
    {
        const int na = lengths[b * 9 + 7] / 4;
        for (int t = tid; t < na; t += BS) {
            int i  = sa[4*t+0];
            int j  = sa[4*t+1];
            int k_ = sa[4*t+2];
            int ty = sa[4*t+3];
            float jx = sc[3*j+0], jy = sc[3*j+1], jz = sc[3*j+2];
            float ux = sc[3*i+0] - jx, uy = sc[3*i+1] - jy, uz = sc[3*i+2] - jz;
            float vx = sc[3*k_+0] - jx, vy = sc[3*k_+1] - jy, vz = sc[3*k_+2] - jz;
            float uv = ux*vx + uy*vy + uz*vz;
            float uu = ux*ux + uy*uy + uz*uz;
            float vv = vx*vx + vy*vy + vz*vz;
            float c  = uv * rsqrtf((uu + EPS) * (vv + EPS));
            c = fminf(fmaxf(c, -1.0f + 1e-6f), 1.0f - 1e-6f);
            float theta = acosf(c);
            float k  = sap[3*ty+0];
            float d  = theta - sap[3*ty+1];
            acc += k * d * d;
        }
    }

    // ---- torsions: E = k * (1 + cos(n*phi - phi0)) ----
    {
        const int nt = lengths[b * 9 + 8] / 5;
        for (int t = tid; t < nt; t += BS) {
            int i  = st[5*t+0];
            int j  = st[5*t+1];
            int k_ = st[5*t+2];
            int l  = st[5*t+3];
            int ty = st[5*t+4];
            float ix = sc[3*i+0],  iy = sc[3*i+1],  iz = sc[3*i+2];
            float jx = sc[3*j+0],  jy = sc[3*j+1],  jz = sc[3*j+2];
            float kx = sc[3*k_+0], ky = sc[3*k_+1], kz = sc[3*k_+2];
            float lx = sc[3*l+0],  ly = sc[3*l+1],  lz = sc[3*l+2];
            float b1x = jx - ix, b1y = jy - iy, b1z = jz - iz;
            float b2x = kx - jx, b2y = ky - jy, b2z = kz - jz;
            float b3x = lx - kx, b3y = ly - ky, b3z = lz - kz;
            float n1x = b1y*b2z - b1z*b2y;
            float n1y = b1z*b2x - b1x*b2z;
            float n1z = b1x*b2y - b1y*b2x;
            float n2x = b2y*b3z - b2z*b3y;
            float n2y = b2z*b3x - b2x*b3z;
            float n2z = b2x*b3y - b2y*b3x;
            float inv = rsqrtf(b2x*b2x + b2y*b2y + b2z*b2z + EPS);
            float hx = b2x * inv, hy = b2y * inv, hz = b2z * inv;
            float m1x = n1y*hz - n1z*hy;
            float m1y = n1z*hx - n1x*hz;
            float m1z = n1x*hy - n1y*hx;
            float sy = m1x*n2x + m1y*n2y + m1z*n2z;
            float sx = n1x*n2x + n1y*n2y + n1z*n2z;
            float phi = atan2f(sy, sx);
            float k  = stp[3*ty+0];
            float p0 = stp[3*ty+1];
            float n  = stp[3*ty+2];
            acc += k * (1.0f + cosf(n * phi - p0));
        }
    }

    // ---- reduce: 64-lane shuffle, then cross-wave via LDS ----
    for (int off = 32; off > 0; off >>= 1)
        acc += __shfl_down(acc, off, 64);
    const int wave = tid >> 6, lane = tid & 63;
    if (lane == 0) sw[wave] = acc;
    __syncthreads();
    if (tid == 0) {
        float s = 0.0f;
        #pragma unroll
        for (int w = 0; w < BS / 64; ++w) s += sw[w];
        out[b] = s;
    }
}

extern "C" void kernel_launch(void* const* d_in, const int* in_sizes, int n_in,
                              void* d_out, int out_size, void* d_ws, size_t ws_size,
                              hipStream_t stream) {
    const float* features   = (const float*)d_in[0];
    const int*   lengths    = (const int*)  d_in[1];
    const float* opt_pars   = (const float*)d_in[2];
    const float* bond_type  = (const float*)d_in[3];
    const float* angle_type = (const float*)d_in[4];
    const float* tor_type   = (const float*)d_in[5];
    float* out = (float*)d_out;

    // 76 KB dynamic LDS (> 64 KB default) — raise the cap every call (cheap,
    // idempotent, capture-safe: not a stream op).
    hipFuncSetAttribute((const void*)energy_kernel,
                        hipFuncAttributeMaxDynamicSharedMemorySize, SMEM_BYTES);

    const int B = out_size;  // 256
    energy_kernel<<<B, BS, SMEM_BYTES, stream>>>(features, lengths, opt_pars,
                                                 bond_type, angle_type,
                                                 tor_type, out);
}